// Round 1
// baseline (147.146 us; speedup 1.0000x reference)
//
#include <hip/hip_runtime.h>
#include <hip/hip_bf16.h>

__device__ __forceinline__ float bf2f(unsigned short u) {
    union { unsigned int i; float f; } v; v.i = ((unsigned int)u) << 16; return v.f;
}
__device__ __forceinline__ unsigned short f2bf(float f) {
    __hip_bfloat16 h = __float2bfloat16(f);
    return *reinterpret_cast<unsigned short*>(&h);
}

// ws: Q fp32 [b][g][pix][ci] (4 MB) | K bf16 (2 MB) | V bf16 (2 MB)

// ---------------------------------------------------------------------------
// conv: three 1x1 convs, fp32 in/weights, fp32 accum.  (unchanged)
// Register-tiled GEMM: block = 128 out-ch x 64 px, thread = 8 ch x 4 px.
// LDS k-major tiles: w_s[k][o] (64x132), x_s[k][px] (64x68). Two K-halves.
// Q -> fp32, K/V -> bf16, layout [b][g][pix][ci]. grid (128 px-tiles, 3).
// ---------------------------------------------------------------------------
__global__ __launch_bounds__(256) void conv_kernel(
    const float* __restrict__ fm,
    const float* __restrict__ wq, const float* __restrict__ wk,
    const float* __restrict__ wv,
    float* __restrict__ Qout,
    unsigned short* __restrict__ K0,
    unsigned short* __restrict__ V0)
{
    const int sel = blockIdx.y;
    const float* W = (sel == 0) ? wq : ((sel == 1) ? wk : wv);
    const int c0 = (sel == 0) ? 128 : 0;   // Q reads fm_t1, K/V read fm_t0

    __shared__ float w_s[64 * 132];   // [k][o], o stride 132
    __shared__ float x_s[64 * 68];    // [k][px], px stride 68

    const int tid = threadIdx.x;
    const int P0  = blockIdx.x * 64;  // one full row of one image
    const int b   = P0 >> 12;
    const int hw0 = P0 & 4095;

    float acc[8][4];
    #pragma unroll
    for (int i = 0; i < 8; ++i)
        #pragma unroll
        for (int j = 0; j < 4; ++j) acc[i][j] = 0.f;

    const int ocb = (tid >> 4) * 8;   // out-ch base (0,8,...,120)
    const int pxb = (tid & 15) * 4;   // px base (0,4,...,60)

    for (int kh = 0; kh < 128; kh += 64) {
        // stage weights transposed: w_s[k][o]
        {
            const int o    = tid >> 1;
            const int koff = (tid & 1) * 32;
            #pragma unroll
            for (int i = 0; i < 8; ++i) {
                float4 v = *(const float4*)(W + o * 128 + kh + koff + i * 4);
                w_s[(koff + i * 4 + 0) * 132 + o] = v.x;
                w_s[(koff + i * 4 + 1) * 132 + o] = v.y;
                w_s[(koff + i * 4 + 2) * 132 + o] = v.z;
                w_s[(koff + i * 4 + 3) * 132 + o] = v.w;
            }
        }
        // stage x: x_s[k][px] — matches global [ch][px] layout, fully vector
        {
            const int c  = tid >> 2;
            const int pc = (tid & 3) * 16;
            const float* src = fm + (((size_t)(b * 256 + c0 + kh + c)) << 12) + hw0 + pc;
            #pragma unroll
            for (int i = 0; i < 4; ++i)
                *(float4*)(&x_s[c * 68 + pc + i * 4]) = *(const float4*)(src + i * 4);
        }
        __syncthreads();
        #pragma unroll 8
        for (int k = 0; k < 64; ++k) {
            const float* kw = &w_s[k * 132 + ocb];
            float4 wa = *(const float4*)kw;
            float4 wb = *(const float4*)(kw + 4);
            float4 xv = *(const float4*)(&x_s[k * 68 + pxb]);
            const float wf[8] = {wa.x, wa.y, wa.z, wa.w, wb.x, wb.y, wb.z, wb.w};
            const float xf[4] = {xv.x, xv.y, xv.z, xv.w};
            #pragma unroll
            for (int i = 0; i < 8; ++i)
                #pragma unroll
                for (int j = 0; j < 4; ++j) acc[i][j] += wf[i] * xf[j];
        }
        __syncthreads();
    }

    // epilogue: out[b][g][pix][ci], g = ocb>>4, ci base = ocb&8
    const int g   = ocb >> 4;
    const int lci = ocb & 8;
    #pragma unroll
    for (int pj = 0; pj < 4; ++pj) {
        const int hw = hw0 + pxb + pj;
        const size_t base = ((((size_t)(b * 8 + g)) << 12) + hw) * 16 + lci;
        if (sel == 0) {
            *(float4*)(Qout + base)     = make_float4(acc[0][pj], acc[1][pj], acc[2][pj], acc[3][pj]);
            *(float4*)(Qout + base + 4) = make_float4(acc[4][pj], acc[5][pj], acc[6][pj], acc[7][pj]);
        } else {
            unsigned short tmp[8];
            #pragma unroll
            for (int i = 0; i < 8; ++i) tmp[i] = f2bf(acc[i][pj]);
            unsigned short* dst = ((sel == 1) ? K0 : V0) + base;
            *(uint4*)dst = *(const uint4*)tmp;
        }
    }
}

// ---------------------------------------------------------------------------
// attn v2: one thread per (b,g,h,w,channel-quarter). 4 lanes per pixel,
// 4 channels per lane. All three parts (main 7x7 + refine row + refine col)
// fused in one thread; plain stores, no atomics, no memset.
// Dots: per-lane 4-ch partial + 2-step __shfl_xor reduce within the 4-lane
// group. Part 0 uses online softmax over window rows (7 scores live, not 49).
// block 256 = 64 px x 4 lanes (one image row); grid (64 rows, 8 g, 2 b).
// ---------------------------------------------------------------------------
__device__ __forceinline__ float dot4(const float* q, const unsigned short* p) {
    uint2 u = *(const uint2*)p;
    const unsigned short* s = (const unsigned short*)&u;
    return q[0] * bf2f(s[0]) + q[1] * bf2f(s[1]) +
           q[2] * bf2f(s[2]) + q[3] * bf2f(s[3]);
}
__device__ __forceinline__ float red4(float s) {
    s += __shfl_xor(s, 1, 64);
    s += __shfl_xor(s, 2, 64);
    return s;
}
__device__ __forceinline__ void axpy4(float* acc, float wgt, const unsigned short* p) {
    uint2 u = *(const uint2*)p;
    const unsigned short* s = (const unsigned short*)&u;
    acc[0] += wgt * bf2f(s[0]);
    acc[1] += wgt * bf2f(s[1]);
    acc[2] += wgt * bf2f(s[2]);
    acc[3] += wgt * bf2f(s[3]);
}

__global__ __launch_bounds__(256) void attn_kernel(
    const float* __restrict__ Q,
    const unsigned short* __restrict__ K0,
    const unsigned short* __restrict__ V0,
    const float* __restrict__ rel_h,
    const float* __restrict__ rel_w,
    float* __restrict__ out)
{
    const int tid = threadIdx.x;
    const int cq  = tid & 3;          // channel quarter (4 ch per lane)
    const int w   = tid >> 2;         // pixel column (64 per block)
    const int h   = blockIdx.x;       // pixel row
    const int g   = blockIdx.y;
    const int b   = blockIdx.z;
    const int cq4 = cq * 4;

    const size_t slab = ((size_t)(b * 8 + g)) << 16;   // 4096 px * 16 ch
    const float* qptr = Q + slab + (size_t)(h * 64 + w) * 16 + cq4;

    float qr[4];
    #pragma unroll
    for (int c = 0; c < 4; ++c) qr[c] = qptr[c];

    const unsigned short* Kp = K0 + slab;
    const unsigned short* Vp = V0 + slab;

    float accT[4];
    #pragma unroll
    for (int c = 0; c < 4; ++c) accT[c] = 0.f;

    // ---- part 0: 7x7 window with rel bias, online softmax over rows ----
    {
        // qrel[t] = q . rel[:,t] over this group's 16 channels
        float qrel[7];
        const float* rel = (g < 4) ? (rel_h + g * 112) : (rel_w + (g - 4) * 112);
        #pragma unroll
        for (int t = 0; t < 7; ++t) {
            float s = 0.f;
            #pragma unroll
            for (int c = 0; c < 4; ++c) s += qr[c] * rel[(cq4 + c) * 7 + t];
            qrel[t] = red4(s);
        }
        const bool bias_i = (g < 4);

        float m = -3.0e38f, den = 0.f;
        float acc[4] = {0.f, 0.f, 0.f, 0.f};
        #pragma unroll
        for (int i = 0; i < 7; ++i) {
            const int y = h + i - 3;
            const bool yin = ((unsigned)y < 64u);
            float s[7];
            #pragma unroll
            for (int j = 0; j < 7; ++j) {
                const int x = w + j - 3;
                float d = 0.f;
                if (yin && (unsigned)x < 64u)
                    d = dot4(qr, Kp + (((size_t)(y * 64 + x)) << 4) + cq4);
                d = red4(d);                       // uniform within 4-lane group
                s[j] = d + (bias_i ? qrel[i] : qrel[j]);
            }
            float rm = s[0];
            #pragma unroll
            for (int j = 1; j < 7; ++j) rm = fmaxf(rm, s[j]);
            const float nm  = fmaxf(m, rm);
            const float scl = __expf(m - nm);
            den *= scl;
            #pragma unroll
            for (int c = 0; c < 4; ++c) acc[c] *= scl;
            #pragma unroll
            for (int j = 0; j < 7; ++j) {
                const float e = __expf(s[j] - nm);
                den += e;
                const int x = w + j - 3;
                if (yin && (unsigned)x < 64u)
                    axpy4(acc, e, Vp + (((size_t)(y * 64 + x)) << 4) + cq4);
            }
            m = nm;
        }
        const float inv = 1.f / den;
        #pragma unroll
        for (int c = 0; c < 4; ++c) accT[c] += acc[c] * inv;
    }

    // ---- part 1: refine row (15 col offsets at row h) ----
    {
        float sc[15];
        float mx = -3.0e38f;
        #pragma unroll
        for (int j = 0; j < 15; ++j) {
            const int x = w + j - 7;
            float d = 0.f;
            if ((unsigned)x < 64u)
                d = dot4(qr, Kp + (((size_t)(h * 64 + x)) << 4) + cq4);
            sc[j] = red4(d);
            mx = fmaxf(mx, sc[j]);
        }
        float den = 0.f;
        #pragma unroll
        for (int j = 0; j < 15; ++j) { sc[j] = __expf(sc[j] - mx); den += sc[j]; }
        const float inv = 1.f / den;
        float acc[4] = {0.f, 0.f, 0.f, 0.f};
        #pragma unroll
        for (int j = 0; j < 15; ++j) {
            const int x = w + j - 7;
            if ((unsigned)x < 64u)
                axpy4(acc, sc[j], Vp + (((size_t)(h * 64 + x)) << 4) + cq4);
        }
        #pragma unroll
        for (int c = 0; c < 4; ++c) accT[c] += acc[c] * inv;
    }

    // ---- part 2: refine col (15 row offsets at col w) ----
    {
        float sc[15];
        float mx = -3.0e38f;
        #pragma unroll
        for (int i = 0; i < 15; ++i) {
            const int y = h + i - 7;
            float d = 0.f;
            if ((unsigned)y < 64u)
                d = dot4(qr, Kp + (((size_t)(y * 64 + w)) << 4) + cq4);
            sc[i] = red4(d);
            mx = fmaxf(mx, sc[i]);
        }
        float den = 0.f;
        #pragma unroll
        for (int i = 0; i < 15; ++i) { sc[i] = __expf(sc[i] - mx); den += sc[i]; }
        const float inv = 1.f / den;
        float acc[4] = {0.f, 0.f, 0.f, 0.f};
        #pragma unroll
        for (int i = 0; i < 15; ++i) {
            const int y = h + i - 7;
            if ((unsigned)y < 64u)
                axpy4(acc, sc[i], Vp + (((size_t)(y * 64 + w)) << 4) + cq4);
        }
        #pragma unroll
        for (int c = 0; c < 4; ++c) accT[c] += acc[c] * inv;
    }

    // store: out[b][g*16 + cq4 + c][h][w]  (full coverage -> no memset needed)
    float* op = out + (((size_t)(b * 128 + g * 16 + cq4)) << 12) + h * 64 + w;
    #pragma unroll
    for (int c = 0; c < 4; ++c)
        op[(size_t)c << 12] = accT[c];
}

// ---------------------------------------------------------------------------
extern "C" void kernel_launch(void* const* d_in, const int* in_sizes, int n_in,
                              void* d_out, int out_size, void* d_ws, size_t ws_size,
                              hipStream_t stream) {
    (void)in_sizes; (void)n_in; (void)ws_size; (void)out_size;
    const float* fm    = (const float*)d_in[0];
    const float* wq    = (const float*)d_in[1];
    const float* wk    = (const float*)d_in[2];
    const float* wv    = (const float*)d_in[3];
    const float* rel_h = (const float*)d_in[4];
    const float* rel_w = (const float*)d_in[5];

    float* Q = (float*)d_ws;                               // 1048576 floats
    unsigned short* K0 = (unsigned short*)(Q + 1048576);   // 1048576 shorts
    unsigned short* V0 = K0 + 1048576;                     // 1048576 shorts

    conv_kernel<<<dim3(128, 3, 1), dim3(256), 0, stream>>>(
        fm, wq, wk, wv, Q, K0, V0);
    attn_kernel<<<dim3(64, 8, 2), dim3(256), 0, stream>>>(
        Q, K0, V0, rel_h, rel_w, (float*)d_out);
}

// Round 4
// 113.571 us; speedup vs baseline: 1.2956x; 1.2956x over previous
//
#include <hip/hip_runtime.h>
#include <hip/hip_bf16.h>

__device__ __forceinline__ float bf2f(unsigned short u) {
    union { unsigned int i; float f; } v; v.i = ((unsigned int)u) << 16; return v.f;
}
__device__ __forceinline__ unsigned short f2bf(float f) {
    __hip_bfloat16 h = __float2bfloat16(f);
    return *reinterpret_cast<unsigned short*>(&h);
}

// ws layout:
//   Q  fp32 [b][g][4096][16]                      4 MB
//   K  bf16 canvas [b][g][80][80][16]             3.2768 MB  (zero-padded)
//   V  bf16 canvas [b][g][80][80][16]             3.2768 MB  (zero-padded)
// Canvas: pixel (h,w) lives at row h+8, col w+8. Rows/cols 1..78 cover
// y,x in [-7,70]; pads are zeroed each iteration (conv(0)=0 == reference).

#define CANVAS_SLAB 102400   // 80*80*16 ushorts per (b,g)

// ---------------------------------------------------------------------------
// pad_zero: zero both K/V canvases with plain stores (no hipMemsetAsync on
// the workspace — only host API touching d_ws is kernel args). conv then
// overwrites the interior. 800 blocks x 256 thr x 16 B = 3.2768 MB x 2? No:
// total = 2 canvases * 16 slabs * 204800 B = 6.5536 MB = 409600 uint4.
// ---------------------------------------------------------------------------
__global__ __launch_bounds__(256) void pad_zero_kernel(uint4* __restrict__ p)
{
    const size_t i = (size_t)blockIdx.x * 256 + threadIdx.x;
    p[i] = make_uint4(0u, 0u, 0u, 0u);   // grid sized exactly: 1600 * 256
}

// ---------------------------------------------------------------------------
// conv: three 1x1 convs, fp32 in/weights, fp32 accum.
// Register-tiled GEMM: block = 128 out-ch x 64 px, thread = 8 ch x 4 px.
// LDS k-major tiles: w_s[k][o] (64x132), x_s[k][px] (64x68). Two K-halves.
// Q -> fp32 packed, K/V -> bf16 into padded canvas. grid (128 px-tiles, 3).
// ---------------------------------------------------------------------------
__global__ __launch_bounds__(256) void conv_kernel(
    const float* __restrict__ fm,
    const float* __restrict__ wq, const float* __restrict__ wk,
    const float* __restrict__ wv,
    float* __restrict__ Qout,
    unsigned short* __restrict__ K0,
    unsigned short* __restrict__ V0)
{
    const int sel = blockIdx.y;
    const float* W = (sel == 0) ? wq : ((sel == 1) ? wk : wv);
    const int c0 = (sel == 0) ? 128 : 0;   // Q reads fm_t1, K/V read fm_t0

    __shared__ float w_s[64 * 132];   // [k][o], o stride 132
    __shared__ float x_s[64 * 68];    // [k][px], px stride 68

    const int tid = threadIdx.x;
    const int P0  = blockIdx.x * 64;  // one full row of one image
    const int b   = P0 >> 12;
    const int hw0 = P0 & 4095;

    float acc[8][4];
    #pragma unroll
    for (int i = 0; i < 8; ++i)
        #pragma unroll
        for (int j = 0; j < 4; ++j) acc[i][j] = 0.f;

    const int ocb = (tid >> 4) * 8;   // out-ch base (0,8,...,120)
    const int pxb = (tid & 15) * 4;   // px base (0,4,...,60)

    for (int kh = 0; kh < 128; kh += 64) {
        // stage weights transposed: w_s[k][o]
        {
            const int o    = tid >> 1;
            const int koff = (tid & 1) * 32;
            #pragma unroll
            for (int i = 0; i < 8; ++i) {
                float4 v = *(const float4*)(W + o * 128 + kh + koff + i * 4);
                w_s[(koff + i * 4 + 0) * 132 + o] = v.x;
                w_s[(koff + i * 4 + 1) * 132 + o] = v.y;
                w_s[(koff + i * 4 + 2) * 132 + o] = v.z;
                w_s[(koff + i * 4 + 3) * 132 + o] = v.w;
            }
        }
        // stage x: x_s[k][px] — matches global [ch][px] layout, fully vector
        {
            const int c  = tid >> 2;
            const int pc = (tid & 3) * 16;
            const float* src = fm + (((size_t)(b * 256 + c0 + kh + c)) << 12) + hw0 + pc;
            #pragma unroll
            for (int i = 0; i < 4; ++i)
                *(float4*)(&x_s[c * 68 + pc + i * 4]) = *(const float4*)(src + i * 4);
        }
        __syncthreads();
        #pragma unroll 8
        for (int k = 0; k < 64; ++k) {
            const float* kw = &w_s[k * 132 + ocb];
            float4 wa = *(const float4*)kw;
            float4 wb = *(const float4*)(kw + 4);
            float4 xv = *(const float4*)(&x_s[k * 68 + pxb]);
            const float wf[8] = {wa.x, wa.y, wa.z, wa.w, wb.x, wb.y, wb.z, wb.w};
            const float xf[4] = {xv.x, xv.y, xv.z, xv.w};
            #pragma unroll
            for (int i = 0; i < 8; ++i)
                #pragma unroll
                for (int j = 0; j < 4; ++j) acc[i][j] += wf[i] * xf[j];
        }
        __syncthreads();
    }

    // epilogue: Q -> packed [b][g][pix][ci]; K/V -> padded canvas.
    const int g   = ocb >> 4;
    const int lci = ocb & 8;
    const int hh  = hw0 >> 6;          // row (constant per block)
    #pragma unroll
    for (int pj = 0; pj < 4; ++pj) {
        const int ww = pxb + pj;
        if (sel == 0) {
            const size_t base = ((((size_t)(b * 8 + g)) << 12) + (hh * 64 + ww)) * 16 + lci;
            *(float4*)(Qout + base)     = make_float4(acc[0][pj], acc[1][pj], acc[2][pj], acc[3][pj]);
            *(float4*)(Qout + base + 4) = make_float4(acc[4][pj], acc[5][pj], acc[6][pj], acc[7][pj]);
        } else {
            const size_t cbase = (size_t)(b * 8 + g) * CANVAS_SLAB
                               + ((size_t)((hh + 8) * 80 + (ww + 8))) * 16 + lci;
            unsigned short tmp[8];
            #pragma unroll
            for (int i = 0; i < 8; ++i) tmp[i] = f2bf(acc[i][pj]);
            unsigned short* dst = ((sel == 1) ? K0 : V0) + cbase;
            *(uint4*)dst = *(const uint4*)tmp;
        }
    }
}

// ---------------------------------------------------------------------------
// attn v3: one thread per (b,g,h,w) per PART (16 ch/thread, no cross-lane).
// part 0 = main 7x7 (rel bias), part 1 = refine row, part 2 = refine col.
// K/V come from the zero-padded canvas -> NO bounds checks, no divergence,
// all loads unconditional and pipelineable. Each part atomically adds its
// softmax-weighted sum into the zero-initialized fp32 output.
// block 256 = 4 rows x 64 cols; grid (16, 8, 6) with z = b*3 + part.
// ---------------------------------------------------------------------------
struct KV16 { uint4 a, b; };
__device__ __forceinline__ KV16 ld16(const unsigned short* p) {
    KV16 r; r.a = *(const uint4*)p; r.b = *(const uint4*)(p + 8); return r;
}
__device__ __forceinline__ float dotq(const float* q, const KV16& k) {
    const unsigned short* u = (const unsigned short*)&k;
    float s = 0.f;
    #pragma unroll
    for (int c = 0; c < 16; ++c) s += q[c] * bf2f(u[c]);
    return s;
}
__device__ __forceinline__ void axpyq(float* acc, float wgt, const KV16& v) {
    const unsigned short* u = (const unsigned short*)&v;
    #pragma unroll
    for (int c = 0; c < 16; ++c) acc[c] += wgt * bf2f(u[c]);
}

__global__ __launch_bounds__(256) void attn_kernel(
    const float* __restrict__ Q,
    const unsigned short* __restrict__ K0,
    const unsigned short* __restrict__ V0,
    const float* __restrict__ rel_h,
    const float* __restrict__ rel_w,
    float* __restrict__ out)
{
    const int tid  = threadIdx.x;
    const int w    = tid & 63;
    const int h    = blockIdx.x * 4 + (tid >> 6);
    const int g    = blockIdx.y;
    const int b    = blockIdx.z / 3;
    const int part = blockIdx.z % 3;

    const size_t slabQ = ((size_t)(b * 8 + g)) << 16;
    const float* qptr = Q + slabQ + (size_t)(h * 64 + w) * 16;

    float qr[16];
    #pragma unroll
    for (int ci = 0; ci < 16; ++ci) qr[ci] = qptr[ci];

    const unsigned short* Kp = K0 + (size_t)(b * 8 + g) * CANVAS_SLAB;
    const unsigned short* Vp = V0 + (size_t)(b * 8 + g) * CANVAS_SLAB;

    // canvas element index for pixel (y, x), y/x may be in [-8, 71]
    #define CIDX(y, x) (((size_t)(((y) + 8) * 80 + ((x) + 8))) << 4)

    float acc[16];
    #pragma unroll
    for (int ci = 0; ci < 16; ++ci) acc[ci] = 0.f;

    if (part == 0) {
        // qrel[t] = q . rel[:,t]; rel_h for g<4 (depends on i), rel_w else (j)
        float qrel[7];
        const float* rel = (g < 4) ? (rel_h + g * 112) : (rel_w + (g - 4) * 112);
        #pragma unroll
        for (int t = 0; t < 7; ++t) {
            float s = 0.f;
            #pragma unroll
            for (int ci = 0; ci < 16; ++ci) s += qr[ci] * rel[ci * 7 + t];
            qrel[t] = s;
        }
        const bool bias_i = (g < 4);
        float sc[49];
        float mx = -3.4e38f;
        #pragma unroll
        for (int i = 0; i < 7; ++i) {
            const int y = h + i - 3;
            #pragma unroll
            for (int j = 0; j < 7; ++j) {
                const int x = w + j - 3;
                float d = dotq(qr, ld16(Kp + CIDX(y, x)));
                d += bias_i ? qrel[i] : qrel[j];
                sc[i * 7 + j] = d;
                mx = fmaxf(mx, d);
            }
        }
        float den = 0.f;
        #pragma unroll
        for (int k = 0; k < 49; ++k) { sc[k] = __expf(sc[k] - mx); den += sc[k]; }
        const float inv = 1.f / den;
        #pragma unroll
        for (int i = 0; i < 7; ++i) {
            const int y = h + i - 3;
            #pragma unroll
            for (int j = 0; j < 7; ++j) {
                const int x = w + j - 3;
                axpyq(acc, sc[i * 7 + j] * inv, ld16(Vp + CIDX(y, x)));
            }
        }
    } else if (part == 1) {
        // refine row (w offsets)
        float sc[15];
        float mx = -3.4e38f;
        #pragma unroll
        for (int j = 0; j < 15; ++j) {
            const int x = w + j - 7;
            const float d = dotq(qr, ld16(Kp + CIDX(h, x)));
            sc[j] = d; mx = fmaxf(mx, d);
        }
        float den = 0.f;
        #pragma unroll
        for (int j = 0; j < 15; ++j) { sc[j] = __expf(sc[j] - mx); den += sc[j]; }
        const float inv = 1.f / den;
        #pragma unroll
        for (int j = 0; j < 15; ++j) {
            const int x = w + j - 7;
            axpyq(acc, sc[j] * inv, ld16(Vp + CIDX(h, x)));
        }
    } else {
        // refine col (h offsets)
        float sc[15];
        float mx = -3.4e38f;
        #pragma unroll
        for (int i = 0; i < 15; ++i) {
            const int y = h + i - 7;
            const float d = dotq(qr, ld16(Kp + CIDX(y, w)));
            sc[i] = d; mx = fmaxf(mx, d);
        }
        float den = 0.f;
        #pragma unroll
        for (int i = 0; i < 15; ++i) { sc[i] = __expf(sc[i] - mx); den += sc[i]; }
        const float inv = 1.f / den;
        #pragma unroll
        for (int i = 0; i < 15; ++i) {
            const int y = h + i - 7;
            axpyq(acc, sc[i] * inv, ld16(Vp + CIDX(y, w)));
        }
    }
    #undef CIDX

    // accumulate: out[b][g*16+ci][h][w] += acc[ci]
    float* op = out + (((size_t)(b * 128 + g * 16)) << 12) + h * 64 + w;
    #pragma unroll
    for (int ci = 0; ci < 16; ++ci)
        atomicAdd(op + ((size_t)ci << 12), acc[ci]);
}

// ---------------------------------------------------------------------------
extern "C" void kernel_launch(void* const* d_in, const int* in_sizes, int n_in,
                              void* d_out, int out_size, void* d_ws, size_t ws_size,
                              hipStream_t stream) {
    (void)in_sizes; (void)n_in; (void)ws_size;
    const float* fm    = (const float*)d_in[0];
    const float* wq    = (const float*)d_in[1];
    const float* wk    = (const float*)d_in[2];
    const float* wv    = (const float*)d_in[3];
    const float* rel_h = (const float*)d_in[4];
    const float* rel_w = (const float*)d_in[5];

    float* Q = (float*)d_ws;                               // 1048576 floats (4 MB)
    unsigned short* K0 = (unsigned short*)(Q + 1048576);   // 16*102400 ushorts
    unsigned short* V0 = K0 + 16 * CANVAS_SLAB;            // 16*102400 ushorts

    // zero output (atomic accumulation). Canvas zeroing is done by a plain
    // store kernel — no hipMemsetAsync aimed at the workspace.
    hipMemsetAsync(d_out, 0, (size_t)out_size * sizeof(float), stream);
    // 2 canvases * 16 slabs * 102400 ushorts = 409600 uint4 -> 1600 blocks
    pad_zero_kernel<<<dim3(1600), dim3(256), 0, stream>>>((uint4*)K0);

    conv_kernel<<<dim3(128, 3, 1), dim3(256), 0, stream>>>(
        fm, wq, wk, wv, Q, K0, V0);
    attn_kernel<<<dim3(16, 8, 6), dim3(256), 0, stream>>>(
        Q, K0, V0, rel_h, rel_w, (float*)d_out);
}

// Round 5
// 111.495 us; speedup vs baseline: 1.3197x; 1.0186x over previous
//
#include <hip/hip_runtime.h>
#include <hip/hip_bf16.h>

__device__ __forceinline__ float bf2f(unsigned short u) {
    union { unsigned int i; float f; } v; v.i = ((unsigned int)u) << 16; return v.f;
}
__device__ __forceinline__ unsigned short f2bf(float f) {
    __hip_bfloat16 h = __float2bfloat16(f);
    return *reinterpret_cast<unsigned short*>(&h);
}

// ws layout:
//   Q  fp32 [b][g][4096][16]                      4 MB
//   K  bf16 canvas [b][g][80][80][16]             3.2768 MB  (zero-padded)
//   V  bf16 canvas [b][g][80][80][16]             3.2768 MB  (zero-padded)
// Canvas: pixel (h,w) lives at row h+8, col w+8. Pads zeroed every iter
// (harness poisons ws); conv(0)=0 == reference zero-padding semantics.

#define CANVAS_SLAB 102400   // 80*80*16 ushorts per (b,g)

// ---------------------------------------------------------------------------
// pad_zero: zero both K/V canvases with plain stores (no hipMemsetAsync on
// the workspace). conv overwrites the interior afterwards.
// grid 1600 x 256 x 16B = 6.5536 MB exactly.
// ---------------------------------------------------------------------------
__global__ __launch_bounds__(256) void pad_zero_kernel(uint4* __restrict__ p)
{
    const size_t i = (size_t)blockIdx.x * 256 + threadIdx.x;
    p[i] = make_uint4(0u, 0u, 0u, 0u);
}

// ---------------------------------------------------------------------------
// conv v2: three 1x1 convs, fp32, register-tiled GEMM.
// Block = 64 out-ch x 64 px (thread = 4 ch x 4 px), K=128 in two halves.
// grid (128 px-tiles, 2 ch-halves, 3 convs) = 768 blocks = 3/CU exactly
// (v1 was 384 blocks = 1.5/CU -> 33% dispatch tail + poor latency hiding).
// LDS: w_s[k][o] 64x68 (17.4 KB) + x_s[k][px] 64x68 (17.4 KB).
// Inner loop per k: 2 x ds_read_b128 -> 16 FMA.
// ---------------------------------------------------------------------------
__global__ __launch_bounds__(256) void conv_kernel(
    const float* __restrict__ fm,
    const float* __restrict__ wq, const float* __restrict__ wk,
    const float* __restrict__ wv,
    float* __restrict__ Qout,
    unsigned short* __restrict__ K0,
    unsigned short* __restrict__ V0)
{
    const int sel = blockIdx.z;
    const int by  = blockIdx.y;            // out-ch half (0: ch 0-63, 1: 64-127)
    const float* W = (sel == 0) ? wq : ((sel == 1) ? wk : wv);
    const int c0 = (sel == 0) ? 128 : 0;   // Q reads fm_t1, K/V read fm_t0

    __shared__ float w_s[64 * 68];    // [k][o], o stride 68
    __shared__ float x_s[64 * 68];    // [k][px], px stride 68

    const int tid = threadIdx.x;
    const int P0  = blockIdx.x * 64;  // one full row of one image
    const int b   = P0 >> 12;
    const int hw0 = P0 & 4095;

    float acc[4][4];
    #pragma unroll
    for (int i = 0; i < 4; ++i)
        #pragma unroll
        for (int j = 0; j < 4; ++j) acc[i][j] = 0.f;

    const int ocb = (tid >> 4) * 4;   // out-ch base within half (0,4,...,60)
    const int pxb = (tid & 15) * 4;   // px base (0,4,...,60)

    for (int kh = 0; kh < 128; kh += 64) {
        // stage weights transposed: w_s[k][o], o in [0,64) of this half
        {
            const int o    = tid >> 2;          // 0..63
            const int koff = (tid & 3) * 16;    // 0,16,32,48
            #pragma unroll
            for (int i = 0; i < 4; ++i) {
                float4 v = *(const float4*)(W + (size_t)(by * 64 + o) * 128 + kh + koff + i * 4);
                w_s[(koff + i * 4 + 0) * 68 + o] = v.x;
                w_s[(koff + i * 4 + 1) * 68 + o] = v.y;
                w_s[(koff + i * 4 + 2) * 68 + o] = v.z;
                w_s[(koff + i * 4 + 3) * 68 + o] = v.w;
            }
        }
        // stage x: x_s[k][px] — matches global [ch][px] layout, fully vector
        {
            const int c  = tid >> 2;            // 0..63
            const int pc = (tid & 3) * 16;      // 0,16,32,48
            const float* src = fm + (((size_t)(b * 256 + c0 + kh + c)) << 12) + hw0 + pc;
            #pragma unroll
            for (int i = 0; i < 4; ++i)
                *(float4*)(&x_s[c * 68 + pc + i * 4]) = *(const float4*)(src + i * 4);
        }
        __syncthreads();
        #pragma unroll 8
        for (int k = 0; k < 64; ++k) {
            float4 wa = *(const float4*)(&w_s[k * 68 + ocb]);
            float4 xv = *(const float4*)(&x_s[k * 68 + pxb]);
            const float wf[4] = {wa.x, wa.y, wa.z, wa.w};
            const float xf[4] = {xv.x, xv.y, xv.z, xv.w};
            #pragma unroll
            for (int i = 0; i < 4; ++i)
                #pragma unroll
                for (int j = 0; j < 4; ++j) acc[i][j] += wf[i] * xf[j];
        }
        __syncthreads();
    }

    // epilogue: Q -> packed [b][g][pix][ci]; K/V -> padded canvas.
    const int oc  = by * 64 + ocb;     // global out-ch base (multiple of 4)
    const int g   = oc >> 4;
    const int lci = oc & 15;           // 0,4,8,12 — stays within one group
    const int hh  = hw0 >> 6;          // row (constant per block)
    #pragma unroll
    for (int pj = 0; pj < 4; ++pj) {
        const int ww = pxb + pj;
        if (sel == 0) {
            const size_t base = ((((size_t)(b * 8 + g)) << 12) + (hh * 64 + ww)) * 16 + lci;
            *(float4*)(Qout + base) = make_float4(acc[0][pj], acc[1][pj], acc[2][pj], acc[3][pj]);
        } else {
            const size_t cbase = (size_t)(b * 8 + g) * CANVAS_SLAB
                               + ((size_t)((hh + 8) * 80 + (ww + 8))) * 16 + lci;
            unsigned short tmp[4];
            #pragma unroll
            for (int i = 0; i < 4; ++i) tmp[i] = f2bf(acc[i][pj]);
            unsigned short* dst = ((sel == 1) ? K0 : V0) + cbase;
            *(uint2*)dst = *(const uint2*)tmp;
        }
    }
}

// ---------------------------------------------------------------------------
// attn v3 (unchanged): one thread per (b,g,h,w) per PART (16 ch/thread).
// part 0 = main 7x7 (rel bias), part 1 = refine row, part 2 = refine col.
// K/V from zero-padded canvas -> no bounds checks, no divergence.
// block 256 = 4 rows x 64 cols; grid (16, 8, 6) with z = b*3 + part.
// ---------------------------------------------------------------------------
struct KV16 { uint4 a, b; };
__device__ __forceinline__ KV16 ld16(const unsigned short* p) {
    KV16 r; r.a = *(const uint4*)p; r.b = *(const uint4*)(p + 8); return r;
}
__device__ __forceinline__ float dotq(const float* q, const KV16& k) {
    const unsigned short* u = (const unsigned short*)&k;
    float s = 0.f;
    #pragma unroll
    for (int c = 0; c < 16; ++c) s += q[c] * bf2f(u[c]);
    return s;
}
__device__ __forceinline__ void axpyq(float* acc, float wgt, const KV16& v) {
    const unsigned short* u = (const unsigned short*)&v;
    #pragma unroll
    for (int c = 0; c < 16; ++c) acc[c] += wgt * bf2f(u[c]);
}

__global__ __launch_bounds__(256) void attn_kernel(
    const float* __restrict__ Q,
    const unsigned short* __restrict__ K0,
    const unsigned short* __restrict__ V0,
    const float* __restrict__ rel_h,
    const float* __restrict__ rel_w,
    float* __restrict__ out)
{
    const int tid  = threadIdx.x;
    const int w    = tid & 63;
    const int h    = blockIdx.x * 4 + (tid >> 6);
    const int g    = blockIdx.y;
    const int b    = blockIdx.z / 3;
    const int part = blockIdx.z % 3;

    const size_t slabQ = ((size_t)(b * 8 + g)) << 16;
    const float* qptr = Q + slabQ + (size_t)(h * 64 + w) * 16;

    float qr[16];
    #pragma unroll
    for (int ci = 0; ci < 16; ++ci) qr[ci] = qptr[ci];

    const unsigned short* Kp = K0 + (size_t)(b * 8 + g) * CANVAS_SLAB;
    const unsigned short* Vp = V0 + (size_t)(b * 8 + g) * CANVAS_SLAB;

    // canvas element index for pixel (y, x), y/x may be in [-8, 71]
    #define CIDX(y, x) (((size_t)(((y) + 8) * 80 + ((x) + 8))) << 4)

    float acc[16];
    #pragma unroll
    for (int ci = 0; ci < 16; ++ci) acc[ci] = 0.f;

    if (part == 0) {
        // qrel[t] = q . rel[:,t]; rel_h for g<4 (depends on i), rel_w else (j)
        float qrel[7];
        const float* rel = (g < 4) ? (rel_h + g * 112) : (rel_w + (g - 4) * 112);
        #pragma unroll
        for (int t = 0; t < 7; ++t) {
            float s = 0.f;
            #pragma unroll
            for (int ci = 0; ci < 16; ++ci) s += qr[ci] * rel[ci * 7 + t];
            qrel[t] = s;
        }
        const bool bias_i = (g < 4);
        float sc[49];
        float mx = -3.4e38f;
        #pragma unroll
        for (int i = 0; i < 7; ++i) {
            const int y = h + i - 3;
            #pragma unroll
            for (int j = 0; j < 7; ++j) {
                const int x = w + j - 3;
                float d = dotq(qr, ld16(Kp + CIDX(y, x)));
                d += bias_i ? qrel[i] : qrel[j];
                sc[i * 7 + j] = d;
                mx = fmaxf(mx, d);
            }
        }
        float den = 0.f;
        #pragma unroll
        for (int k = 0; k < 49; ++k) { sc[k] = __expf(sc[k] - mx); den += sc[k]; }
        const float inv = 1.f / den;
        #pragma unroll
        for (int i = 0; i < 7; ++i) {
            const int y = h + i - 3;
            #pragma unroll
            for (int j = 0; j < 7; ++j) {
                const int x = w + j - 3;
                axpyq(acc, sc[i * 7 + j] * inv, ld16(Vp + CIDX(y, x)));
            }
        }
    } else if (part == 1) {
        // refine row (w offsets)
        float sc[15];
        float mx = -3.4e38f;
        #pragma unroll
        for (int j = 0; j < 15; ++j) {
            const int x = w + j - 7;
            const float d = dotq(qr, ld16(Kp + CIDX(h, x)));
            sc[j] = d; mx = fmaxf(mx, d);
        }
        float den = 0.f;
        #pragma unroll
        for (int j = 0; j < 15; ++j) { sc[j] = __expf(sc[j] - mx); den += sc[j]; }
        const float inv = 1.f / den;
        #pragma unroll
        for (int j = 0; j < 15; ++j) {
            const int x = w + j - 7;
            axpyq(acc, sc[j] * inv, ld16(Vp + CIDX(h, x)));
        }
    } else {
        // refine col (h offsets)
        float sc[15];
        float mx = -3.4e38f;
        #pragma unroll
        for (int i = 0; i < 15; ++i) {
            const int y = h + i - 7;
            const float d = dotq(qr, ld16(Kp + CIDX(y, w)));
            sc[i] = d; mx = fmaxf(mx, d);
        }
        float den = 0.f;
        #pragma unroll
        for (int i = 0; i < 15; ++i) { sc[i] = __expf(sc[i] - mx); den += sc[i]; }
        const float inv = 1.f / den;
        #pragma unroll
        for (int i = 0; i < 15; ++i) {
            const int y = h + i - 7;
            axpyq(acc, sc[i] * inv, ld16(Vp + CIDX(y, w)));
        }
    }
    #undef CIDX

    // accumulate: out[b][g*16+ci][h][w] += acc[ci]
    float* op = out + (((size_t)(b * 128 + g * 16)) << 12) + h * 64 + w;
    #pragma unroll
    for (int ci = 0; ci < 16; ++ci)
        atomicAdd(op + ((size_t)ci << 12), acc[ci]);
}

// ---------------------------------------------------------------------------
extern "C" void kernel_launch(void* const* d_in, const int* in_sizes, int n_in,
                              void* d_out, int out_size, void* d_ws, size_t ws_size,
                              hipStream_t stream) {
    (void)in_sizes; (void)n_in; (void)ws_size;
    const float* fm    = (const float*)d_in[0];
    const float* wq    = (const float*)d_in[1];
    const float* wk    = (const float*)d_in[2];
    const float* wv    = (const float*)d_in[3];
    const float* rel_h = (const float*)d_in[4];
    const float* rel_w = (const float*)d_in[5];

    float* Q = (float*)d_ws;                               // 1048576 floats (4 MB)
    unsigned short* K0 = (unsigned short*)(Q + 1048576);   // 16*102400 ushorts
    unsigned short* V0 = K0 + 16 * CANVAS_SLAB;            // 16*102400 ushorts

    // zero output (atomic accumulation). Canvas zeroing via plain stores.
    hipMemsetAsync(d_out, 0, (size_t)out_size * sizeof(float), stream);
    pad_zero_kernel<<<dim3(1600), dim3(256), 0, stream>>>((uint4*)K0);

    conv_kernel<<<dim3(128, 2, 3), dim3(256), 0, stream>>>(
        fm, wq, wk, wv, Q, K0, V0);
    attn_kernel<<<dim3(16, 8, 6), dim3(256), 0, stream>>>(
        Q, K0, V0, rel_h, rel_w, (float*)d_out);
}